// Round 1
// baseline (209.746 us; speedup 1.0000x reference)
//
#include <hip/hip_runtime.h>
#include <stdint.h>

// N = D*H*W = 8*32*32 voxels; C = 64 channels.
constexpr int N = 8192;
// softmax scale (1/sqrt(64)) * log2(e), folded into Q at projection time so the
// attention kernel works directly in exp2 domain (v_exp_f32 is 2^x).
constexpr float QSCALE = 0.18033688011112042f;

typedef __attribute__((ext_vector_type(4))) float f32x4;
typedef __attribute__((ext_vector_type(4))) unsigned int u32x4;

// round-to-nearest-even f32 -> bf16 bits (self-contained, no header struct deps)
__device__ inline unsigned short f2bf(float f) {
  unsigned u = __builtin_bit_cast(unsigned, f);
  u += 0x7FFFu + ((u >> 16) & 1u);
  return (unsigned short)(u >> 16);
}

// D = A*B + D, 16x16x32 bf16 MFMA via inline asm (avoids builtin arg-type ambiguity).
// A: lane holds A[lane&15][8*(lane>>4)+e]; B: lane holds B[8*(lane>>4)+e][lane&15];
// D: lane,reg r -> D[4*(lane>>4)+r][lane&15]   (verified m89 layout)
__device__ inline void mfma16x16x32bf16(f32x4& d, u32x4 a, u32x4 b) {
  asm volatile("v_mfma_f32_16x16x32_bf16 %0, %1, %2, %0"
               : "+v"(d)
               : "v"(a), "v"(b));
}

struct ProjArgs {
  const float* x[6];
  const float* w[6];
  const float* b[6];
  unsigned short* o[6];
  int mode[6];     // 0: out[n][64] (Q^T / K^T row-per-voxel)  1: out[c][N] (V channel-major)
  float scale[6];
};

// ---- 1x1x1 conv projections: Y = W X + b, X = [64][N] f32, all six in one launch.
__global__ __launch_bounds__(256) void proj_kernel(ProjArgs A) {
  const int p = blockIdx.y;
  const float* __restrict__ x = A.x[p];
  const float* __restrict__ w = A.w[p];
  const float* __restrict__ bias = A.b[p];
  unsigned short* __restrict__ out = A.o[p];
  const int n0 = blockIdx.x * 128;
  __shared__ float Xs[64][128];   // 32 KB
  __shared__ float Ws[64][64];    // 16 KB
  const int t = threadIdx.x;
#pragma unroll
  for (int i = 0; i < 4; i++) {          // W: 4096 f32 = 1024 16B slots
    int s = t + i * 256;
    ((u32x4*)Ws)[s] = ((const u32x4*)w)[s];
  }
#pragma unroll
  for (int i = 0; i < 8; i++) {          // X tile: 64x128 f32 = 2048 slots
    int s = t + i * 256;
    int c = s >> 5, nc = s & 31;
    *(u32x4*)&Xs[c][nc * 4] = *(const u32x4*)&x[c * N + n0 + nc * 4];
  }
  __syncthreads();
  const int n = t & 127, h = t >> 7;     // h: o-half (uniform per wave)
  float acc[32];
#pragma unroll
  for (int o = 0; o < 32; o++) acc[o] = bias[h * 32 + o];
  for (int c = 0; c < 64; c++) {
    float xv = Xs[c][n];
#pragma unroll
    for (int o = 0; o < 32; o++) acc[o] = fmaf(Ws[h * 32 + o][c], xv, acc[o]);
  }
  const float sc = A.scale[p];
  if (A.mode[p] == 0) {
    unsigned short* po = out + (size_t)(n0 + n) * 64 + h * 32;
#pragma unroll
    for (int o = 0; o < 32; o++) po[o] = f2bf(acc[o] * sc);
  } else {
#pragma unroll
    for (int o = 0; o < 32; o++) out[(size_t)(h * 32 + o) * N + n0 + n] = f2bf(acc[o] * sc);
  }
}

// ---- fused flash cross-attention. Per block: 64 Q-rows (4 waves x 16), loop over
// 128 KV tiles of 64. O is accumulated transposed (O^T = V * P^T) so the P fragment
// needed is exactly the A-layout fragment and fused output lands channel-major.
__global__ __launch_bounds__(256) void attn_kernel(
    const unsigned short* __restrict__ Q0, const unsigned short* __restrict__ K0,
    const unsigned short* __restrict__ V0, const unsigned short* __restrict__ Q1,
    const unsigned short* __restrict__ K1, const unsigned short* __restrict__ V1,
    float* __restrict__ fused) {
  const int dir = blockIdx.y;
  const unsigned short* __restrict__ Q = dir ? Q1 : Q0;
  const unsigned short* __restrict__ K = dir ? K1 : K0;
  const unsigned short* __restrict__ V = dir ? V1 : V0;
  const int qt = blockIdx.x;
  __shared__ unsigned short Klds[4096];  // [j][c] bf16, XOR-swizzled, 8 KB
  __shared__ unsigned short Vlds[4096];  // [c][j] bf16, XOR-swizzled, 8 KB
  __shared__ unsigned short Plds[4096];  // per-wave 16x64 P tile, 8 KB
  const int t = threadIdx.x;
  const int lane = t & 63, wv = t >> 6;
  const int g = lane >> 4, sl = lane & 15;
  const int swz = (sl & 7) << 4;
  const int iq = qt * 64 + wv * 16 + sl;  // this lane's Q row / O^T column

  // Q A-fragments (held for whole kernel): Qt[n][64] bf16, row = iq
  u32x4 qf0, qf1;
  {
    const char* qrow = (const char*)Q + (size_t)iq * 128;
    qf0 = *(const u32x4*)(qrow + g * 16);
    qf1 = *(const u32x4*)(qrow + 64 + g * 16);
  }
  f32x4 acc_o[4];
#pragma unroll
  for (int mb = 0; mb < 4; mb++)
#pragma unroll
    for (int r = 0; r < 4; r++) acc_o[mb][r] = 0.f;
  float m_run[4], lpart[4];
#pragma unroll
  for (int r = 0; r < 4; r++) { m_run[r] = -1e30f; lpart[r] = 0.f; }

  for (int jt = 0; jt < 128; jt++) {
    const int j0 = jt * 64;
    // -- stage K tile (Kt[j0..][64] is one contiguous 8KB block) + V tile, swizzled
    {
      const u32x4* __restrict__ ksrc = (const u32x4*)(K + (size_t)j0 * 64);
#pragma unroll
      for (int q2 = 0; q2 < 2; q2++) {
        int s = t + q2 * 256;
        int row = s >> 3, ch = s & 7, chs = ch ^ (row & 7);
        u32x4 val = ksrc[row * 8 + chs];
        *(u32x4*)((char*)Klds + row * 128 + ch * 16) = val;
      }
#pragma unroll
      for (int q2 = 0; q2 < 2; q2++) {
        int s = t + q2 * 256;
        int row = s >> 3, ch = s & 7, chs = ch ^ (row & 7);
        u32x4 val = *(const u32x4*)(V + (size_t)row * N + j0 + chs * 8);
        *(u32x4*)((char*)Vlds + row * 128 + ch * 16) = val;
      }
    }
    __syncthreads();

    // -- QK^T: S[i][j], 4 j-blocks x 2 k-steps
    f32x4 s_acc[4];
#pragma unroll
    for (int jb = 0; jb < 4; jb++) {
#pragma unroll
      for (int r = 0; r < 4; r++) s_acc[jb][r] = 0.f;
      int jrow = jb * 16 + sl;
      u32x4 kf0 = *(const u32x4*)((const char*)Klds + ((jrow * 128 + g * 16) ^ swz));
      u32x4 kf1 = *(const u32x4*)((const char*)Klds + ((jrow * 128 + 64 + g * 16) ^ swz));
      mfma16x16x32bf16(s_acc[jb], qf0, kf0);
      mfma16x16x32bf16(s_acc[jb], qf1, kf1);
    }

    // -- online softmax (exp2 domain; scale pre-folded into Q)
    float tmax[4];
#pragma unroll
    for (int r = 0; r < 4; r++)
      tmax[r] = fmaxf(fmaxf(s_acc[0][r], s_acc[1][r]), fmaxf(s_acc[2][r], s_acc[3][r]));
#pragma unroll
    for (int r = 0; r < 4; r++) {
#pragma unroll
      for (int mask = 1; mask <= 8; mask <<= 1)
        tmax[r] = fmaxf(tmax[r], __shfl_xor(tmax[r], mask));
    }
    float corr[4];
#pragma unroll
    for (int r = 0; r < 4; r++) {
      float mnew = fmaxf(m_run[r], tmax[r]);
      corr[r] = __builtin_amdgcn_exp2f(m_run[r] - mnew);
      m_run[r] = mnew;
    }
    unsigned short* __restrict__ Pw = Plds + wv * 1024;
    float psum[4] = {0.f, 0.f, 0.f, 0.f};
#pragma unroll
    for (int jb = 0; jb < 4; jb++) {
#pragma unroll
      for (int r = 0; r < 4; r++) {
        float pv = __builtin_amdgcn_exp2f(s_acc[jb][r] - m_run[r]);
        psum[r] += pv;
        int row_p = 4 * g + r;
        int off = (row_p * 128 + (jb * 16 + sl) * 2) ^ ((row_p & 7) << 4);
        *(unsigned short*)((char*)Pw + off) = f2bf(pv);
      }
    }
#pragma unroll
    for (int r = 0; r < 4; r++) lpart[r] = lpart[r] * corr[r] + psum[r];

    // -- rescale O^T: lane's column is row i = sl; fetch corr for that row
    {
      int src = (sl >> 2) << 4;
      float c0 = __shfl(corr[0], src);
      float c1 = __shfl(corr[1], src);
      float c2 = __shfl(corr[2], src);
      float c3 = __shfl(corr[3], src);
      int rr = sl & 3;
      float ci = rr == 0 ? c0 : (rr == 1 ? c1 : (rr == 2 ? c2 : c3));
#pragma unroll
      for (int mb = 0; mb < 4; mb++)
#pragma unroll
        for (int r = 0; r < 4; r++) acc_o[mb][r] *= ci;
    }

    // -- PV: O^T += V * P^T  (P fragment == A-layout fragment of P)
    {
      u32x4 pf0 = *(const u32x4*)((const char*)Pw + ((sl * 128 + g * 16) ^ swz));
      u32x4 pf1 = *(const u32x4*)((const char*)Pw + ((sl * 128 + 64 + g * 16) ^ swz));
#pragma unroll
      for (int mb = 0; mb < 4; mb++) {
        int crow = mb * 16 + sl;
        u32x4 vf0 = *(const u32x4*)((const char*)Vlds + ((crow * 128 + g * 16) ^ swz));
        u32x4 vf1 = *(const u32x4*)((const char*)Vlds + ((crow * 128 + 64 + g * 16) ^ swz));
        mfma16x16x32bf16(acc_o[mb], vf0, pf0);
        mfma16x16x32bf16(acc_o[mb], vf1, pf1);
      }
    }
    __syncthreads();
  }

  // -- finalize: row sums, normalize, write fused[ch][n] (channel-major f32)
#pragma unroll
  for (int r = 0; r < 4; r++) {
#pragma unroll
    for (int mask = 1; mask <= 8; mask <<= 1)
      lpart[r] += __shfl_xor(lpart[r], mask);
  }
  int src = (sl >> 2) << 4;
  float l0 = __shfl(lpart[0], src);
  float l1 = __shfl(lpart[1], src);
  float l2 = __shfl(lpart[2], src);
  float l3 = __shfl(lpart[3], src);
  int rr = sl & 3;
  float li = rr == 0 ? l0 : (rr == 1 ? l1 : (rr == 2 ? l2 : l3));
  float rli = 1.0f / li;
  float* __restrict__ fo = fused + (size_t)dir * 64 * N + (size_t)qt * 64 + wv * 16 + sl;
#pragma unroll
  for (int mb = 0; mb < 4; mb++)
#pragma unroll
    for (int r = 0; r < 4; r++)
      fo[(size_t)(mb * 16 + 4 * g + r) * N] = acc_o[mb][r] * rli;
}

// ---- output projection: out[o][n] = wo[o][0:128] . fused[:][n] + bo[o]
__global__ __launch_bounds__(256) void oproj_kernel(
    const float* __restrict__ fused, const float* __restrict__ wo,
    const float* __restrict__ bo, float* __restrict__ out) {
  __shared__ float Fs[128][64];   // 32 KB
  __shared__ float Ws[64][128];   // 32 KB
  const int t = threadIdx.x;
  const int n0 = blockIdx.x * 64;
#pragma unroll
  for (int i = 0; i < 8; i++) {
    int s = t + i * 256;
    ((u32x4*)Ws)[s] = ((const u32x4*)wo)[s];
  }
#pragma unroll
  for (int i = 0; i < 8; i++) {
    int s = t + i * 256;
    int ch = s >> 4, nc = s & 15;
    *(u32x4*)&Fs[ch][nc * 4] = *(const u32x4*)&fused[(size_t)ch * N + n0 + nc * 4];
  }
  __syncthreads();
  const int n = t & 63, h = t >> 6;
  float acc[16];
#pragma unroll
  for (int o = 0; o < 16; o++) acc[o] = bo[h * 16 + o];
  for (int ch = 0; ch < 128; ch++) {
    float fv = Fs[ch][n];
#pragma unroll
    for (int o = 0; o < 16; o++) acc[o] = fmaf(Ws[h * 16 + o][ch], fv, acc[o]);
  }
#pragma unroll
  for (int o = 0; o < 16; o++) out[(size_t)(h * 16 + o) * N + n0 + n] = acc[o];
}

extern "C" void kernel_launch(void* const* d_in, const int* in_sizes, int n_in,
                              void* d_out, int out_size, void* d_ws, size_t ws_size,
                              hipStream_t stream) {
  const float* ct     = (const float*)d_in[0];
  const float* mri    = (const float*)d_in[1];
  const float* wq_ct  = (const float*)d_in[2];
  const float* bq_ct  = (const float*)d_in[3];
  const float* wk_mri = (const float*)d_in[4];
  const float* bk_mri = (const float*)d_in[5];
  const float* wv_mri = (const float*)d_in[6];
  const float* bv_mri = (const float*)d_in[7];
  const float* wq_mri = (const float*)d_in[8];
  const float* bq_mri = (const float*)d_in[9];
  const float* wk_ct  = (const float*)d_in[10];
  const float* bk_ct  = (const float*)d_in[11];
  const float* wv_ct  = (const float*)d_in[12];
  const float* bv_ct  = (const float*)d_in[13];
  const float* wo     = (const float*)d_in[14];
  const float* bo     = (const float*)d_in[15];

  // workspace layout (needs 10 MB): 6 x 1MB bf16 projections + 4MB f32 fused
  char* ws = (char*)d_ws;
  const size_t MB = (size_t)1 << 20;
  unsigned short* Qt_ct  = (unsigned short*)(ws + 0 * MB);  // [n][64] bf16, pre-scaled
  unsigned short* Kt_mri = (unsigned short*)(ws + 1 * MB);  // [n][64] bf16
  unsigned short* V_mri  = (unsigned short*)(ws + 2 * MB);  // [c][N] bf16
  unsigned short* Qt_mri = (unsigned short*)(ws + 3 * MB);
  unsigned short* Kt_ct  = (unsigned short*)(ws + 4 * MB);
  unsigned short* V_ct   = (unsigned short*)(ws + 5 * MB);
  float* fused           = (float*)(ws + 6 * MB);           // [128][N] f32

  ProjArgs A;
  A.x[0] = ct;  A.w[0] = wq_ct;  A.b[0] = bq_ct;  A.o[0] = Qt_ct;  A.mode[0] = 0; A.scale[0] = QSCALE;
  A.x[1] = mri; A.w[1] = wk_mri; A.b[1] = bk_mri; A.o[1] = Kt_mri; A.mode[1] = 0; A.scale[1] = 1.f;
  A.x[2] = mri; A.w[2] = wv_mri; A.b[2] = bv_mri; A.o[2] = V_mri;  A.mode[2] = 1; A.scale[2] = 1.f;
  A.x[3] = mri; A.w[3] = wq_mri; A.b[3] = bq_mri; A.o[3] = Qt_mri; A.mode[3] = 0; A.scale[3] = QSCALE;
  A.x[4] = ct;  A.w[4] = wk_ct;  A.b[4] = bk_ct;  A.o[4] = Kt_ct;  A.mode[4] = 0; A.scale[4] = 1.f;
  A.x[5] = ct;  A.w[5] = wv_ct;  A.b[5] = bv_ct;  A.o[5] = V_ct;   A.mode[5] = 1; A.scale[5] = 1.f;

  proj_kernel<<<dim3(64, 6), 256, 0, stream>>>(A);
  attn_kernel<<<dim3(128, 2), 256, 0, stream>>>(Qt_ct, Kt_mri, V_mri, Qt_mri, Kt_ct, V_ct, fused);
  oproj_kernel<<<dim3(128), 256, 0, stream>>>(fused, wo, bo, (float*)d_out);
}

// Round 2
// 136.632 us; speedup vs baseline: 1.5351x; 1.5351x over previous
//
#include <hip/hip_runtime.h>
#include <stdint.h>

// N = D*H*W = 8*32*32 voxels; C = 64 channels.
constexpr int N = 8192;
// softmax scale (1/sqrt(64)) * log2(e), folded into Q (attn works in exp2 domain).
constexpr float QSCALE = 0.18033688011112042f;
constexpr int SPLIT = 4;   // cross-block KV split (blockIdx.y); in-block split 2 -> 8 chunks total

typedef __attribute__((ext_vector_type(4))) float f32x4;
typedef __attribute__((ext_vector_type(4))) unsigned int u32x4;
typedef __attribute__((ext_vector_type(4))) unsigned short u16x4;

__device__ inline unsigned short f2bf(float f) {
  unsigned u = __builtin_bit_cast(unsigned, f);
  u += 0x7FFFu + ((u >> 16) & 1u);
  return (unsigned short)(u >> 16);
}
__device__ inline float bf2f(unsigned short u) {
  return __builtin_bit_cast(float, (unsigned)u << 16);
}

// D = A*B + D, 16x16x32 bf16. A: lane holds A[lane&15][8*(lane>>4)+e];
// B: lane holds B[8*(lane>>4)+e][lane&15]; D: D[4*(lane>>4)+r][lane&15]. (m89, R0-verified)
__device__ inline void mfma16x16x32bf16(f32x4& d, u32x4 a, u32x4 b) {
  asm volatile("v_mfma_f32_16x16x32_bf16 %0, %1, %2, %0" : "+v"(d) : "v"(a), "v"(b));
}

struct ProjArgs {
  const float* x[6];
  const float* w[6];
  const float* b[6];
  unsigned short* o[6];
  int mode[6];     // 0: out[n][64]   1: out[c][N]
  float scale[6];
};

// ---- 1x1x1 conv projections (unchanged from R1; not the bottleneck).
__global__ __launch_bounds__(256) void proj_kernel(ProjArgs A) {
  const int p = blockIdx.y;
  const float* __restrict__ x = A.x[p];
  const float* __restrict__ w = A.w[p];
  const float* __restrict__ bias = A.b[p];
  unsigned short* __restrict__ out = A.o[p];
  const int n0 = blockIdx.x * 128;
  __shared__ float Xs[64][128];
  __shared__ float Ws[64][64];
  const int t = threadIdx.x;
#pragma unroll
  for (int i = 0; i < 4; i++) {
    int s = t + i * 256;
    ((u32x4*)Ws)[s] = ((const u32x4*)w)[s];
  }
#pragma unroll
  for (int i = 0; i < 8; i++) {
    int s = t + i * 256;
    int c = s >> 5, nc = s & 31;
    *(u32x4*)&Xs[c][nc * 4] = *(const u32x4*)&x[c * N + n0 + nc * 4];
  }
  __syncthreads();
  const int n = t & 127, h = t >> 7;
  float acc[32];
#pragma unroll
  for (int o = 0; o < 32; o++) acc[o] = bias[h * 32 + o];
  for (int c = 0; c < 64; c++) {
    float xv = Xs[c][n];
#pragma unroll
    for (int o = 0; o < 32; o++) acc[o] = fmaf(Ws[h * 32 + o][c], xv, acc[o]);
  }
  const float sc = A.scale[p];
  if (A.mode[p] == 0) {
    unsigned short* po = out + (size_t)(n0 + n) * 64 + h * 32;
#pragma unroll
    for (int o = 0; o < 32; o++) po[o] = f2bf(acc[o] * sc);
  } else {
#pragma unroll
    for (int o = 0; o < 32; o++) out[(size_t)(h * 32 + o) * N + n0 + n] = f2bf(acc[o] * sc);
  }
}

// ---- flash cross-attention, swapped-QK variant.
// Block: 256 thr = 4 waves = {qsub 0..1} x {cw 0..1}. Wave: 32 Q rows, KV chunk of 1024.
// Total KV split = 8 (blockIdx.y*2 + cw); in-block flash-merge of the 2 cw partials;
// per-(dir,chunkpair) partial O^T (bf16) + (m,l) to workspace; merge_kernel combines 4.
__global__ __launch_bounds__(256, 3) void attn_kernel(
    const unsigned short* __restrict__ Q0, const unsigned short* __restrict__ K0,
    const unsigned short* __restrict__ V0, const unsigned short* __restrict__ Q1,
    const unsigned short* __restrict__ K1, const unsigned short* __restrict__ V1,
    unsigned short* __restrict__ Opart, float* __restrict__ Ml) {
  const int dir = blockIdx.z;
  const unsigned short* __restrict__ Q = dir ? Q1 : Q0;
  const unsigned short* __restrict__ K = dir ? K1 : K0;
  const unsigned short* __restrict__ V = dir ? V1 : V0;
  const int qb = blockIdx.x;      // 128 tiles of 64 Q rows
  const int cpair = blockIdx.y;   // 0..3

  __shared__ char smem[32768];    // [0,16K): Klds[2][64][64] bf16 swz; [16K,32K): Pt[4][32][64]

  const int t = threadIdx.x;
  const int lane = t & 63, w = t >> 6;
  const int qsub = w >> 1, cw = w & 1;
  const int chunk = cpair * 2 + cw;
  const int kvbase = chunk * 1024;
  const int g = lane >> 4, sl = lane & 15;

  // Q^T B-fragments (held whole kernel): qf[rb][ks] = Q[qrow][ks*32+8g .. +8]
  u32x4 qf[2][2];
#pragma unroll
  for (int rb = 0; rb < 2; rb++) {
    const int qrow = qb * 64 + qsub * 32 + rb * 16 + sl;
#pragma unroll
    for (int ks = 0; ks < 2; ks++)
      qf[rb][ks] = *(const u32x4*)(Q + (size_t)qrow * 64 + ks * 32 + 8 * g);
  }

  f32x4 acc[4][2];   // O^T[mb*16+4g+r][rb*16+sl]
#pragma unroll
  for (int mb = 0; mb < 4; mb++)
#pragma unroll
    for (int rb = 0; rb < 2; rb++)
#pragma unroll
      for (int r = 0; r < 4; r++) acc[mb][rb][r] = 0.f;
  float m_run[2] = {-1e30f, -1e30f}, lrun[2] = {0.f, 0.f};

  // staging lanes: this wave stages 4 x 16B slots of its cw's K tile per iteration
  const int srow0 = (qsub * 256 + lane) >> 3;   // rows advance by 8 per i
  const int scl = lane & 7;
  char* const kl = smem + cw * 8192;
  char* const pw = smem + 16384 + w * 4096;

  // prologue: stage tile 0
  u32x4 stg[4];
#pragma unroll
  for (int i = 0; i < 4; i++) {
    int row = srow0 + i * 8;
    stg[i] = *(const u32x4*)(K + (size_t)(kvbase + row) * 64 + (scl ^ (row & 7)) * 8);
  }
#pragma unroll
  for (int i = 0; i < 4; i++) {
    int s = qsub * 256 + i * 64 + lane;
    *(u32x4*)(kl + s * 16) = stg[i];
  }

  for (int jt = 0; jt < 16; ++jt) {
    const int j0 = kvbase + jt * 64;
    __syncthreads();   // K tile staged (drains all mem ops)

    // QK^T (swapped): st[jb][rb] = S^T[jb*16+4g+r][rb*16+sl]
    f32x4 st[4][2];
#pragma unroll
    for (int jb = 0; jb < 4; jb++) {
      const int row = jb * 16 + sl;
      const int swz = (row & 7) << 4;
      u32x4 kf0 = *(const u32x4*)(kl + row * 128 + ((16 * g) ^ swz));
      u32x4 kf1 = *(const u32x4*)(kl + row * 128 + ((64 + 16 * g) ^ swz));
#pragma unroll
      for (int rb = 0; rb < 2; rb++) {
#pragma unroll
        for (int r = 0; r < 4; r++) st[jb][rb][r] = 0.f;
        mfma16x16x32bf16(st[jb][rb], kf0, qf[rb][0]);
        mfma16x16x32bf16(st[jb][rb], kf1, qf[rb][1]);
      }
    }
    __syncthreads();   // all QK reads of Klds done -> safe to restage

    // issue next tile's staging loads (consumed at end of iter; latency hides under SM+PV)
    if (jt + 1 < 16) {
      const int nb = kvbase + (jt + 1) * 64;
#pragma unroll
      for (int i = 0; i < 4; i++) {
        int row = srow0 + i * 8;
        stg[i] = *(const u32x4*)(K + (size_t)(nb + row) * 64 + (scl ^ (row & 7)) * 8);
      }
    }

    // online softmax (exp2 domain), per q-column = rb*16+sl (lane-local!)
#pragma unroll
    for (int rb = 0; rb < 2; rb++) {
      float tm = fmaxf(fmaxf(st[0][rb][0], st[0][rb][1]), fmaxf(st[0][rb][2], st[0][rb][3]));
#pragma unroll
      for (int jb = 1; jb < 4; jb++) {
        float a = fmaxf(fmaxf(st[jb][rb][0], st[jb][rb][1]),
                        fmaxf(st[jb][rb][2], st[jb][rb][3]));
        tm = fmaxf(tm, a);
      }
      tm = fmaxf(tm, __shfl_xor(tm, 16));
      tm = fmaxf(tm, __shfl_xor(tm, 32));
      float mnew = fmaxf(m_run[rb], tm);
      float corr = __builtin_amdgcn_exp2f(m_run[rb] - mnew);
      m_run[rb] = mnew;
      float sum = 0.f;
#pragma unroll
      for (int jb = 0; jb < 4; jb++) {
#pragma unroll
        for (int r = 0; r < 4; r++) {
          float pv = __builtin_amdgcn_exp2f(st[jb][rb][r] - mnew);
          st[jb][rb][r] = pv;
          sum += pv;
        }
      }
      sum += __shfl_xor(sum, 16);
      sum += __shfl_xor(sum, 32);
      lrun[rb] = lrun[rb] * corr + sum;
#pragma unroll
      for (int mb = 0; mb < 4; mb++)
#pragma unroll
        for (int r = 0; r < 4; r++) acc[mb][rb][r] *= corr;
      // P^T store: 4 consecutive j per lane -> b64, conflict-free in 8-lane groups
      const int q = rb * 16 + sl;
      const int qswz = (q & 7) << 4;
#pragma unroll
      for (int jb = 0; jb < 4; jb++) {
        u16x4 pk;
        pk[0] = f2bf(st[jb][rb][0]); pk[1] = f2bf(st[jb][rb][1]);
        pk[2] = f2bf(st[jb][rb][2]); pk[3] = f2bf(st[jb][rb][3]);
        *(u16x4*)(pw + q * 128 + ((jb * 32 + 8 * g) ^ qswz)) = pk;
      }
    }

    // PV: O^T += V * P^T.  V A-frags direct from global (L2-resident).
    u32x4 pf[2][2];
#pragma unroll
    for (int rb = 0; rb < 2; rb++) {
      const int q = rb * 16 + sl;
      const int qswz = (q & 7) << 4;
#pragma unroll
      for (int ks = 0; ks < 2; ks++)
        pf[rb][ks] = *(const u32x4*)(pw + q * 128 + ((ks * 64 + 16 * g) ^ qswz));
    }
#pragma unroll
    for (int mb = 0; mb < 4; mb++) {
      u32x4 vf0 = *(const u32x4*)(V + (size_t)(mb * 16 + sl) * N + j0 + 8 * g);
      u32x4 vf1 = *(const u32x4*)(V + (size_t)(mb * 16 + sl) * N + j0 + 32 + 8 * g);
#pragma unroll
      for (int rb = 0; rb < 2; rb++) {
        mfma16x16x32bf16(acc[mb][rb], vf0, pf[rb][0]);
        mfma16x16x32bf16(acc[mb][rb], vf1, pf[rb][1]);
      }
    }

    // write next K tile into LDS (reads were fenced by 2nd barrier)
    if (jt + 1 < 16) {
#pragma unroll
      for (int i = 0; i < 4; i++) {
        int s = qsub * 256 + i * 64 + lane;
        *(u32x4*)(kl + s * 16) = stg[i];
      }
    }
  }

  // ---- in-block merge of the two cw partials (overlay on Klds/Pt areas)
  __syncthreads();
  char* const obuf = smem + qsub * 8192;           // [32 q][64 ch] f32, swizzled
  float* const mlb = (float*)(smem + 16384 + qsub * 512);
  if (cw == 1) {
#pragma unroll
    for (int rb = 0; rb < 2; rb++) {
      const int q = rb * 16 + sl;
      const int qswz = (q & 7) << 4;
#pragma unroll
      for (int mb = 0; mb < 4; mb++)
        *(f32x4*)(obuf + q * 256 + (((mb * 16 + 4 * g) * 4) ^ qswz)) = acc[mb][rb];
      if (g == 0) { mlb[q * 2] = m_run[rb]; mlb[q * 2 + 1] = lrun[rb]; }
    }
  }
  __syncthreads();
  if (cw == 0) {
#pragma unroll
    for (int rb = 0; rb < 2; rb++) {
      const int q = rb * 16 + sl;
      const int qswz = (q & 7) << 4;
      const float m1 = mlb[q * 2], l1 = mlb[q * 2 + 1];
      const float M = fmaxf(m_run[rb], m1);
      const float e0 = __builtin_amdgcn_exp2f(m_run[rb] - M);
      const float e1 = __builtin_amdgcn_exp2f(m1 - M);
      const float lz = e0 * lrun[rb] + e1 * l1;
      const int qg = qb * 64 + qsub * 32 + q;
      const size_t pbase = ((size_t)(dir * SPLIT + cpair) * N + qg) * 64;
#pragma unroll
      for (int mb = 0; mb < 4; mb++) {
        f32x4 oo = *(const f32x4*)(obuf + q * 256 + (((mb * 16 + 4 * g) * 4) ^ qswz));
        u16x4 pk;
#pragma unroll
        for (int r = 0; r < 4; r++) pk[r] = f2bf(acc[mb][rb][r] * e0 + oo[r] * e1);
        *(u16x4*)(Opart + pbase + mb * 16 + 4 * g) = pk;
      }
      if (g == 0) {
        const size_t mi = ((size_t)(dir * SPLIT + cpair) * N + qg) * 2;
        Ml[mi] = M; Ml[mi + 1] = lz;
      }
    }
  }
}

// ---- combine the 4 chunk-pair partials -> fused[128][N] f32
__global__ __launch_bounds__(256) void merge_kernel(
    const unsigned short* __restrict__ Opart, const float* __restrict__ Ml,
    float* __restrict__ fused) {
  const int t = threadIdx.x;
  const int dir = blockIdx.y;
  const int q = blockIdx.x * 64 + (t & 63);
  const int chg = t >> 6;   // 16 channels per thread
  float m[4], l[4];
#pragma unroll
  for (int c = 0; c < 4; c++) {
    size_t mi = ((size_t)(dir * SPLIT + c) * N + q) * 2;
    m[c] = Ml[mi]; l[c] = Ml[mi + 1];
  }
  float M = fmaxf(fmaxf(m[0], m[1]), fmaxf(m[2], m[3]));
  float e[4], D = 0.f;
#pragma unroll
  for (int c = 0; c < 4; c++) { e[c] = __builtin_amdgcn_exp2f(m[c] - M); D += e[c] * l[c]; }
  const float rD = 1.0f / D;
  float o[16];
#pragma unroll
  for (int k = 0; k < 16; k++) o[k] = 0.f;
#pragma unroll
  for (int c = 0; c < 4; c++) {
    const u16x4* p = (const u16x4*)(Opart + ((size_t)(dir * SPLIT + c) * N + q) * 64 + chg * 16);
#pragma unroll
    for (int k4 = 0; k4 < 4; k4++) {
      u16x4 v = p[k4];
#pragma unroll
      for (int e4 = 0; e4 < 4; e4++) o[k4 * 4 + e4] += e[c] * bf2f(v[e4]);
    }
  }
#pragma unroll
  for (int k = 0; k < 16; k++)
    fused[(size_t)(dir * 64 + chg * 16 + k) * N + q] = o[k] * rD;
}

// ---- output projection (unchanged from R1)
__global__ __launch_bounds__(256) void oproj_kernel(
    const float* __restrict__ fused, const float* __restrict__ wo,
    const float* __restrict__ bo, float* __restrict__ out) {
  __shared__ float Fs[128][64];
  __shared__ float Ws[64][128];
  const int t = threadIdx.x;
  const int n0 = blockIdx.x * 64;
#pragma unroll
  for (int i = 0; i < 8; i++) {
    int s = t + i * 256;
    ((u32x4*)Ws)[s] = ((const u32x4*)wo)[s];
  }
#pragma unroll
  for (int i = 0; i < 8; i++) {
    int s = t + i * 256;
    int ch = s >> 4, nc = s & 15;
    *(u32x4*)&Fs[ch][nc * 4] = *(const u32x4*)&fused[(size_t)ch * N + n0 + nc * 4];
  }
  __syncthreads();
  const int n = t & 63, h = t >> 6;
  float acc[16];
#pragma unroll
  for (int o = 0; o < 16; o++) acc[o] = bo[h * 16 + o];
  for (int ch = 0; ch < 128; ch++) {
    float fv = Fs[ch][n];
#pragma unroll
    for (int o = 0; o < 16; o++) acc[o] = fmaf(Ws[h * 16 + o][ch], fv, acc[o]);
  }
#pragma unroll
  for (int o = 0; o < 16; o++) out[(size_t)(h * 16 + o) * N + n0 + n] = acc[o];
}

extern "C" void kernel_launch(void* const* d_in, const int* in_sizes, int n_in,
                              void* d_out, int out_size, void* d_ws, size_t ws_size,
                              hipStream_t stream) {
  const float* ct     = (const float*)d_in[0];
  const float* mri    = (const float*)d_in[1];
  const float* wq_ct  = (const float*)d_in[2];
  const float* bq_ct  = (const float*)d_in[3];
  const float* wk_mri = (const float*)d_in[4];
  const float* bk_mri = (const float*)d_in[5];
  const float* wv_mri = (const float*)d_in[6];
  const float* bv_mri = (const float*)d_in[7];
  const float* wq_mri = (const float*)d_in[8];
  const float* bq_mri = (const float*)d_in[9];
  const float* wk_ct  = (const float*)d_in[10];
  const float* bk_ct  = (const float*)d_in[11];
  const float* wv_ct  = (const float*)d_in[12];
  const float* bv_ct  = (const float*)d_in[13];
  const float* wo     = (const float*)d_in[14];
  const float* bo     = (const float*)d_in[15];

  // ws layout (19 MB): [0,6M) 6x1MB bf16 projections; [6M,14M) Opart bf16
  // (2 dir x 4 chunkpair x 8192 x 64); [14M,14.5M) Ml f32; [15M,19M) fused f32.
  char* ws = (char*)d_ws;
  const size_t MB = (size_t)1 << 20;
  unsigned short* Qt_ct  = (unsigned short*)(ws + 0 * MB);  // [n][64], pre-scaled
  unsigned short* Kt_mri = (unsigned short*)(ws + 1 * MB);  // [n][64]
  unsigned short* V_mri  = (unsigned short*)(ws + 2 * MB);  // [c][N]
  unsigned short* Qt_mri = (unsigned short*)(ws + 3 * MB);
  unsigned short* Kt_ct  = (unsigned short*)(ws + 4 * MB);
  unsigned short* V_ct   = (unsigned short*)(ws + 5 * MB);
  unsigned short* Opart  = (unsigned short*)(ws + 6 * MB);
  float* Ml              = (float*)(ws + 14 * MB);
  float* fused           = (float*)(ws + 15 * MB);

  ProjArgs A;
  A.x[0] = ct;  A.w[0] = wq_ct;  A.b[0] = bq_ct;  A.o[0] = Qt_ct;  A.mode[0] = 0; A.scale[0] = QSCALE;
  A.x[1] = mri; A.w[1] = wk_mri; A.b[1] = bk_mri; A.o[1] = Kt_mri; A.mode[1] = 0; A.scale[1] = 1.f;
  A.x[2] = mri; A.w[2] = wv_mri; A.b[2] = bv_mri; A.o[2] = V_mri;  A.mode[2] = 1; A.scale[2] = 1.f;
  A.x[3] = mri; A.w[3] = wq_mri; A.b[3] = bq_mri; A.o[3] = Qt_mri; A.mode[3] = 0; A.scale[3] = QSCALE;
  A.x[4] = ct;  A.w[4] = wk_ct;  A.b[4] = bk_ct;  A.o[4] = Kt_ct;  A.mode[4] = 0; A.scale[4] = 1.f;
  A.x[5] = ct;  A.w[5] = wv_ct;  A.b[5] = bv_ct;  A.o[5] = V_ct;   A.mode[5] = 1; A.scale[5] = 1.f;

  proj_kernel<<<dim3(64, 6), 256, 0, stream>>>(A);
  attn_kernel<<<dim3(128, SPLIT, 2), 256, 0, stream>>>(Qt_ct, Kt_mri, V_mri,
                                                       Qt_mri, Kt_ct, V_ct, Opart, Ml);
  merge_kernel<<<dim3(128, 2), 256, 0, stream>>>(Opart, Ml, fused);
  oproj_kernel<<<dim3(128), 256, 0, stream>>>(fused, wo, bo, (float*)d_out);
}